// Round 1
// 176.669 us; speedup vs baseline: 1.0467x; 1.0467x over previous
//
#include <hip/hip_runtime.h>
#include <stdint.h>

#define IN_F   8192
#define OUT_F  8192
#define BATCH  1024
#define BT     8              // batch rows staged in LDS per workgroup (16B/row)
#define NBT    (BATCH / BT)   // 128 batch tiles
#define MAIN_THREADS 1024     // 16 waves; 128KB LDS -> 1 WG/CU = 4 waves/SIMD
#define GROUPS_PER_WAVE 4     // 16 waves x 4 groups = 64 groups = half the columns
#define L_PREF 160            // ELL slots/column (max column count ~120; P(>160)~0)
#define XTILE_BYTES (IN_F * 16)   // 128 KB dynamic LDS
#define CSTRIDE 16            // counts padded to 16 dwords = 1 counter per 64B line
                              // (2.68M device-scope atomics over 512 lines serialized
                              //  same-line; padding spreads them over 8192 lines)

#if __has_builtin(__builtin_amdgcn_fdot2) && __has_builtin(__builtin_amdgcn_perm)
#define USE_DOT2 1
typedef _Float16 half2v __attribute__((ext_vector_type(2)));
#else
#define USE_DOT2 0
#endif

typedef float f32x2 __attribute__((ext_vector_type(2)));

// workspace dword layout: counts[8192*CSTRIDE] | ELL slabs (group g at base + g*L*64)

__device__ __forceinline__ unsigned f32_to_bf16_bits_rne(float f) {
    union { float f; unsigned u; } v; v.f = f;
    unsigned u = v.u;
    unsigned r = u + 0x7FFFu + ((u >> 16) & 1u);
    return r >> 16;
}
__device__ __forceinline__ float bf16_hi_bits_to_f32(unsigned b) {
    union { unsigned u; float f; } v; v.u = b & 0xFFFF0000u; return v.f;
}
// packed bf16 pair (x1<<16|x0) -> float2 {x0, x1}
__device__ __forceinline__ f32x2 unpack_pair(unsigned u) {
    union { unsigned u; float f; } lo, hi;
    lo.u = u << 16; hi.u = u & 0xFFFF0000u;
    f32x2 r; r.x = lo.f; r.y = hi.f; return r;
}

#if USE_DOT2
// weight value stored as f16 bits (more mantissa than bf16; vals ~N(0,1)/90 fit easily)
__device__ __forceinline__ unsigned val_bits(float f) {
    return (unsigned)__builtin_bit_cast(unsigned short, (_Float16)f);
}
__device__ __forceinline__ unsigned x_bits(float f) {
    return (unsigned)__builtin_bit_cast(unsigned short, (_Float16)f);
}
#else
__device__ __forceinline__ unsigned val_bits(float f) { return f32_to_bf16_bits_rne(f); }
__device__ __forceinline__ unsigned x_bits(float f)   { return f32_to_bf16_bits_rne(f); }
#endif

// Scatter nnz into fixed-stride ELL.
// Entry = (val16 << 16) | (row << 3). counts[] (line-padded) doubles as cursor;
// afterwards holds per-column counts for spmm trip computation.
__global__ void scatter_kernel(const int* __restrict__ rows, const int* __restrict__ cols,
                               const float* __restrict__ vals,
                               int* __restrict__ counts, unsigned* __restrict__ ell,
                               int nnz, int L) {
    int t = blockIdx.x * blockDim.x + threadIdx.x;
    int i0 = t * 4;
    if (i0 + 3 < nnz) {
        int4   r4 = *(const int4*)(rows + i0);
        int4   c4 = *(const int4*)(cols + i0);
        float4 v4 = *(const float4*)(vals + i0);
        int c0 = c4.x, c1 = c4.y, c2 = c4.z, c3 = c4.w;
        unsigned pk0 = (val_bits(v4.x) << 16) | ((unsigned)r4.x << 3);
        unsigned pk1 = (val_bits(v4.y) << 16) | ((unsigned)r4.y << 3);
        unsigned pk2 = (val_bits(v4.z) << 16) | ((unsigned)r4.z << 3);
        unsigned pk3 = (val_bits(v4.w) << 16) | ((unsigned)r4.w << 3);
        int s0 = atomicAdd(&counts[c0 * CSTRIDE], 1);
        int s1 = atomicAdd(&counts[c1 * CSTRIDE], 1);
        int s2 = atomicAdd(&counts[c2 * CSTRIDE], 1);
        int s3 = atomicAdd(&counts[c3 * CSTRIDE], 1);
        if (s0 < L) ell[(size_t)(c0 >> 6) * (L * 64) + ((s0 >> 2) << 8) + ((c0 & 63) << 2) + (s0 & 3)] = pk0;
        if (s1 < L) ell[(size_t)(c1 >> 6) * (L * 64) + ((s1 >> 2) << 8) + ((c1 & 63) << 2) + (s1 & 3)] = pk1;
        if (s2 < L) ell[(size_t)(c2 >> 6) * (L * 64) + ((s2 >> 2) << 8) + ((c2 & 63) << 2) + (s2 & 3)] = pk2;
        if (s3 < L) ell[(size_t)(c3 >> 6) * (L * 64) + ((s3 >> 2) << 8) + ((c3 & 63) << 2) + (s3 & 3)] = pk3;
    } else {
        for (int i = i0; i < nnz; ++i) {
            int c = cols[i];
            unsigned pk = (val_bits(vals[i]) << 16) | ((unsigned)rows[i] << 3);
            int s = atomicAdd(&counts[c * CSTRIDE], 1);
            if (s < L)
                ell[(size_t)(c >> 6) * (L * 64) + ((s >> 2) << 8) + ((c & 63) << 2) + (s & 3)] = pk;
        }
    }
}

#if USE_DOT2
// Process TWO ELL entries (same column, adjacent slots) against 8 staged batch rows:
// 2x ds_read_b128 + 9x v_perm_b32 + 8x v_dot2_f32_f16  (21 VALU / 2 entries,
// vs 32 for the bf16 unpack+pk_fma path).
__device__ __forceinline__ void process_pair8(unsigned pk0, unsigned pk1, const char* xbase,
        float& a0, float& a1, float& a2, float& a3,
        float& a4, float& a5, float& a6, float& a7) {
    unsigned off0 = pk0 & 0xFFF8u;               // row*8; LDS stride is 16 -> *2
    unsigned off1 = pk1 & 0xFFF8u;
    uint4 q0 = *(const uint4*)(xbase + off0 * 2);  // 8 f16: x[b0..b0+7][r0]
    uint4 q1 = *(const uint4*)(xbase + off1 * 2);  // 8 f16: x[b0..b0+7][r1]
    // vh = (val0, val1): hi16 of pk0 -> lo half, hi16 of pk1 -> hi half
    unsigned vv = __builtin_amdgcn_perm(pk1, pk0, 0x07060302u);
    half2v vh = __builtin_bit_cast(half2v, vv);
    // per dword j: lo halves are batch 2j, hi halves are batch 2j+1
    unsigned e0 = __builtin_amdgcn_perm(q1.x, q0.x, 0x05040100u);  // (x[b0][r0], x[b0][r1])
    unsigned o0 = __builtin_amdgcn_perm(q1.x, q0.x, 0x07060302u);  // (x[b1][r0], x[b1][r1])
    unsigned e1 = __builtin_amdgcn_perm(q1.y, q0.y, 0x05040100u);
    unsigned o1 = __builtin_amdgcn_perm(q1.y, q0.y, 0x07060302u);
    unsigned e2 = __builtin_amdgcn_perm(q1.z, q0.z, 0x05040100u);
    unsigned o2 = __builtin_amdgcn_perm(q1.z, q0.z, 0x07060302u);
    unsigned e3 = __builtin_amdgcn_perm(q1.w, q0.w, 0x05040100u);
    unsigned o3 = __builtin_amdgcn_perm(q1.w, q0.w, 0x07060302u);
    a0 = __builtin_amdgcn_fdot2(__builtin_bit_cast(half2v, e0), vh, a0, false);
    a1 = __builtin_amdgcn_fdot2(__builtin_bit_cast(half2v, o0), vh, a1, false);
    a2 = __builtin_amdgcn_fdot2(__builtin_bit_cast(half2v, e1), vh, a2, false);
    a3 = __builtin_amdgcn_fdot2(__builtin_bit_cast(half2v, o1), vh, a3, false);
    a4 = __builtin_amdgcn_fdot2(__builtin_bit_cast(half2v, e2), vh, a4, false);
    a5 = __builtin_amdgcn_fdot2(__builtin_bit_cast(half2v, o2), vh, a5, false);
    a6 = __builtin_amdgcn_fdot2(__builtin_bit_cast(half2v, e3), vh, a6, false);
    a7 = __builtin_amdgcn_fdot2(__builtin_bit_cast(half2v, o3), vh, a7, false);
}
#else
// Fallback: one ELL entry vs 8 staged batch rows (bf16 unpack + v_pk_fma_f32)
__device__ __forceinline__ void process_entry8(unsigned pk, const char* xbase,
                                               f32x2& a01, f32x2& a23, f32x2& a45, f32x2& a67) {
    float val = bf16_hi_bits_to_f32(pk);
    f32x2 vv; vv.x = val; vv.y = val;
    unsigned off = pk & 0xFFF8u;
    uint4 d = *(const uint4*)(xbase + off * 2);
    a01 = __builtin_elementwise_fma(unpack_pair(d.x), vv, a01);
    a23 = __builtin_elementwise_fma(unpack_pair(d.y), vv, a23);
    a45 = __builtin_elementwise_fma(unpack_pair(d.z), vv, a45);
    a67 = __builtin_elementwise_fma(unpack_pair(d.w), vv, a67);
}
#endif

// Main SpMM: WG = (batch tile of 8) x (half the columns). 16 waves x 4 groups.
// 128KB dynamic LDS holds x[b0..b0+7, :] as uint4 (8 x 16-bit) per input row.
__global__ __launch_bounds__(MAIN_THREADS) void spmm_kernel(
        const float* __restrict__ x,
        const float* __restrict__ bias,
        const int* __restrict__ counts,
        const unsigned* __restrict__ ell,
        float* __restrict__ out, int L) {
    extern __shared__ uint4 xl[];               // IN_F entries = 128 KB
    int w = blockIdx.x;
    int bt = w >> 1;
    int half = w & 1;
    int t = threadIdx.x;
    int b0 = bt * BT;

    for (int r = t; r < IN_F; r += MAIN_THREADS) {
        unsigned u0 = x_bits(x[(b0 + 0) * IN_F + r]);
        unsigned u1 = x_bits(x[(b0 + 1) * IN_F + r]);
        unsigned u2 = x_bits(x[(b0 + 2) * IN_F + r]);
        unsigned u3 = x_bits(x[(b0 + 3) * IN_F + r]);
        unsigned u4 = x_bits(x[(b0 + 4) * IN_F + r]);
        unsigned u5 = x_bits(x[(b0 + 5) * IN_F + r]);
        unsigned u6 = x_bits(x[(b0 + 6) * IN_F + r]);
        unsigned u7 = x_bits(x[(b0 + 7) * IN_F + r]);
        uint4 d;
        d.x = (u1 << 16) | u0;
        d.y = (u3 << 16) | u2;
        d.z = (u5 << 16) | u4;
        d.w = (u7 << 16) | u6;
        xl[r] = d;
    }
    __syncthreads();

    const char* xbase = (const char*)xl;
    int wave = t >> 6;
    int lane = t & 63;
    int n4cap = L >> 2;

#pragma unroll 1
    for (int it = 0; it < GROUPS_PER_WAVE; ++it) {
        int g = half * 64 + wave * GROUPS_PER_WAVE + it;
        int col = (g << 6) + lane;
        int cnt = counts[col * CSTRIDE];
#pragma unroll
        for (int off = 32; off; off >>= 1) cnt = max(cnt, __shfl_xor(cnt, off, 64));
        int n4 = (cnt + 3) >> 2;
        n4 = min(n4, n4cap);
        const uint4* ep = (const uint4*)(ell + (size_t)g * (L * 64));
        float bv = bias[col];
#if USE_DOT2
        float a0 = 0.f, a1 = 0.f, a2 = 0.f, a3 = 0.f;
        float a4 = 0.f, a5 = 0.f, a6 = 0.f, a7 = 0.f;
        if (n4 > 0) {
            uint4 q = ep[lane];
#pragma unroll 1
            for (int s4 = 1; s4 < n4; ++s4) {
                uint4 qn = ep[s4 * 64 + lane];   // prefetch next (independent of q)
                process_pair8(q.x, q.y, xbase, a0, a1, a2, a3, a4, a5, a6, a7);
                process_pair8(q.z, q.w, xbase, a0, a1, a2, a3, a4, a5, a6, a7);
                q = qn;
            }
            process_pair8(q.x, q.y, xbase, a0, a1, a2, a3, a4, a5, a6, a7);
            process_pair8(q.z, q.w, xbase, a0, a1, a2, a3, a4, a5, a6, a7);
        }
        out[(size_t)(b0 + 0) * OUT_F + col] = a0 + bv;
        out[(size_t)(b0 + 1) * OUT_F + col] = a1 + bv;
        out[(size_t)(b0 + 2) * OUT_F + col] = a2 + bv;
        out[(size_t)(b0 + 3) * OUT_F + col] = a3 + bv;
        out[(size_t)(b0 + 4) * OUT_F + col] = a4 + bv;
        out[(size_t)(b0 + 5) * OUT_F + col] = a5 + bv;
        out[(size_t)(b0 + 6) * OUT_F + col] = a6 + bv;
        out[(size_t)(b0 + 7) * OUT_F + col] = a7 + bv;
#else
        f32x2 a01 = {0.f, 0.f}, a23 = {0.f, 0.f}, a45 = {0.f, 0.f}, a67 = {0.f, 0.f};
        if (n4 > 0) {
            uint4 q = ep[lane];
#pragma unroll 1
            for (int s4 = 1; s4 < n4; ++s4) {
                uint4 qn = ep[s4 * 64 + lane];
                process_entry8(q.x, xbase, a01, a23, a45, a67);
                process_entry8(q.y, xbase, a01, a23, a45, a67);
                process_entry8(q.z, xbase, a01, a23, a45, a67);
                process_entry8(q.w, xbase, a01, a23, a45, a67);
                q = qn;
            }
            process_entry8(q.x, xbase, a01, a23, a45, a67);
            process_entry8(q.y, xbase, a01, a23, a45, a67);
            process_entry8(q.z, xbase, a01, a23, a45, a67);
            process_entry8(q.w, xbase, a01, a23, a45, a67);
        }
        out[(size_t)(b0 + 0) * OUT_F + col] = a01.x + bv;
        out[(size_t)(b0 + 1) * OUT_F + col] = a01.y + bv;
        out[(size_t)(b0 + 2) * OUT_F + col] = a23.x + bv;
        out[(size_t)(b0 + 3) * OUT_F + col] = a23.y + bv;
        out[(size_t)(b0 + 4) * OUT_F + col] = a45.x + bv;
        out[(size_t)(b0 + 5) * OUT_F + col] = a45.y + bv;
        out[(size_t)(b0 + 6) * OUT_F + col] = a67.x + bv;
        out[(size_t)(b0 + 7) * OUT_F + col] = a67.y + bv;
#endif
    }
}

extern "C" void kernel_launch(void* const* d_in, const int* in_sizes, int n_in,
                              void* d_out, int out_size, void* d_ws, size_t ws_size,
                              hipStream_t stream) {
    const float* x      = (const float*)d_in[0];
    const float* values = (const float*)d_in[1];
    const float* bias   = (const float*)d_in[2];
    const int* rows = (const int*)d_in[3];
    const int* cols = (const int*)d_in[4];
    float* out = (float*)d_out;
    int nnz = in_sizes[1];

    int* counts = (int*)d_ws;                            // 8192*CSTRIDE dwords (512KB)
    unsigned* ell = (unsigned*)counts + 8192 * CSTRIDE;  // slabs: g*L*64 dwords

    // L = slots per column, multiple of 4, clamped to workspace capacity.
    long long cap_slots = ((long long)(ws_size / 4) - 8192LL * CSTRIDE) / 8192;
    int L = (int)(cap_slots & ~3LL);
    if (L > L_PREF) L = L_PREF;
    if (L < 4) L = 4;

    size_t zero_bytes = (size_t)(8192 * CSTRIDE + (size_t)L * 8192) * 4;  // counts + ELL

    static int attr_set = -1;                    // host-side only; no device effect
    if (attr_set < 0) {
        hipFuncSetAttribute((const void*)spmm_kernel,
                            hipFuncAttributeMaxDynamicSharedMemorySize, XTILE_BYTES);
        attr_set = 1;
    }

    hipMemsetAsync(d_ws, 0, zero_bytes, stream);
    int nthreads = (nnz + 3) / 4;
    scatter_kernel<<<(nthreads + 255) / 256, 256, 0, stream>>>(rows, cols, values,
                                                               counts, ell, nnz, L);
    spmm_kernel<<<NBT * 2, MAIN_THREADS, XTILE_BYTES, stream>>>(x, bias, counts, ell, out, L);
}

// Round 2
// 162.086 us; speedup vs baseline: 1.1408x; 1.0900x over previous
//
#include <hip/hip_runtime.h>
#include <stdint.h>

#define IN_F   8192
#define OUT_F  8192
#define BATCH  1024
#define BT     8              // batch rows staged in LDS per workgroup (16B/row)
#define NBT    (BATCH / BT)   // 128 batch tiles
#define MAIN_THREADS 1024     // 16 waves; 128KB LDS -> 1 WG/CU = 4 waves/SIMD
#define GROUPS_PER_WAVE 4     // 16 waves x 4 groups = 64 groups = half the columns
#define L_PREF 160            // ELL slots/column (max column count ~120; P(>160)~0)
#define XTILE_BYTES (IN_F * 16)   // 128 KB dynamic LDS

// --- two-phase ELL construction ---
#define NBUCKET 1024          // bucket = col >> 3 (8 columns/bucket)
#define P1_THREADS 1024
#define P1_PER 8
#define P1_CHUNK (P1_THREADS * P1_PER)   // 8192 entries per phase-1 block
#define P2_THREADS 1024
#define BIN_STRIDE (L_PREF + 1)          // 161 (odd -> LDS bank spread)

#if __has_builtin(__builtin_amdgcn_fdot2) && __has_builtin(__builtin_amdgcn_perm)
#define USE_DOT2 1
typedef _Float16 half2v __attribute__((ext_vector_type(2)));
#else
#define USE_DOT2 0
#endif

typedef float f32x2 __attribute__((ext_vector_type(2)));

// workspace dword layout: bcnt[1024] | counts[8192] | ELL slabs (bucket b at b*8L)

__device__ __forceinline__ unsigned f32_to_bf16_bits_rne(float f) {
    union { float f; unsigned u; } v; v.f = f;
    unsigned u = v.u;
    unsigned r = u + 0x7FFFu + ((u >> 16) & 1u);
    return r >> 16;
}
__device__ __forceinline__ float bf16_hi_bits_to_f32(unsigned b) {
    union { unsigned u; float f; } v; v.u = b & 0xFFFF0000u; return v.f;
}
__device__ __forceinline__ f32x2 unpack_pair(unsigned u) {
    union { unsigned u; float f; } lo, hi;
    lo.u = u << 16; hi.u = u & 0xFFFF0000u;
    f32x2 r; r.x = lo.f; r.y = hi.f; return r;
}

#if USE_DOT2
// weight value stored as f16 bits (more mantissa than bf16; vals ~N(0,1)/90 fit easily)
__device__ __forceinline__ unsigned val_bits(float f) {
    return (unsigned)__builtin_bit_cast(unsigned short, (_Float16)f);
}
__device__ __forceinline__ unsigned x_bits(float f) {
    return (unsigned)__builtin_bit_cast(unsigned short, (_Float16)f);
}
#else
__device__ __forceinline__ unsigned val_bits(float f) { return f32_to_bf16_bits_rne(f); }
__device__ __forceinline__ unsigned x_bits(float f)   { return f32_to_bf16_bits_rne(f); }
#endif

// ---------------- Phase 1: bin COO entries by col>>3 into bucket slabs ----------------
// Entry = (val16 << 16) | (row << 3) | (col & 7)  -- low 3 bits carry column-in-bucket;
// spmm masks them off (pk & 0xFFF8) so they are free payload.
// Per block: LDS ranks (ds atomics) + block prefix + ONE global atomic per bucket,
// then staged, coalesced run writes into ell[b*8L + idx].
__global__ __launch_bounds__(P1_THREADS) void bin_kernel(
        const int* __restrict__ rows, const int* __restrict__ cols,
        const float* __restrict__ vals,
        int* __restrict__ bcnt, unsigned* __restrict__ ell, int nnz, int L) {
    __shared__ int lcnt[NBUCKET];
    __shared__ int lbase[NBUCKET];
    __shared__ int gbase[NBUCKET];
    __shared__ int wsum[16];
    __shared__ unsigned stage[P1_CHUNK];          // 32KB
    __shared__ unsigned short smap[P1_CHUNK];     // 16KB: staged pos -> bucket

    int tid = threadIdx.x;
    int i0 = blockIdx.x * P1_CHUNK;
    lcnt[tid] = 0;                                // NBUCKET == P1_THREADS
    __syncthreads();

    unsigned mypk[P1_PER];
    int      myb[P1_PER];
    int      myrk[P1_PER];
#pragma unroll
    for (int k = 0; k < P1_PER; ++k) {
        int i = i0 + k * P1_THREADS + tid;
        myb[k] = -1;
        mypk[k] = 0;
        myrk[k] = 0;
        if (i < nnz) {
            int c = cols[i];
            mypk[k] = (val_bits(vals[i]) << 16) | ((unsigned)rows[i] << 3) | ((unsigned)c & 7u);
            myb[k] = c >> 3;
            myrk[k] = atomicAdd(&lcnt[c >> 3], 1);
        }
    }
    __syncthreads();

    // block-wide exclusive prefix of lcnt -> lbase
    {
        int wv = tid >> 6, ln = tid & 63;
        int v = lcnt[tid];
        int sc = v;
#pragma unroll
        for (int off = 1; off < 64; off <<= 1) {
            int o = __shfl_up(sc, off, 64);
            if (ln >= off) sc += o;
        }
        if (ln == 63) wsum[wv] = sc;
        __syncthreads();
        if (tid < 16) {
            int s = wsum[tid];
            int sl = s;
#pragma unroll
            for (int off = 1; off < 16; off <<= 1) {
                int o = __shfl_up(sl, off, 16);
                if (tid >= off) sl += o;
            }
            wsum[tid] = sl - s;                   // exclusive wave base
        }
        __syncthreads();
        lbase[tid] = sc - v + wsum[wv];
    }
    __syncthreads();

    // reserve global ranges: one device atomic per (block,bucket)
    {
        int lc = lcnt[tid];
        gbase[tid] = lc ? atomicAdd(&bcnt[tid], lc) : 0;
    }
    // stage entries into per-bucket runs in LDS
#pragma unroll
    for (int k = 0; k < P1_PER; ++k) {
        if (myb[k] >= 0) {
            int pos = lbase[myb[k]] + myrk[k];
            stage[pos] = mypk[k];
            smap[pos] = (unsigned short)myb[k];
        }
    }
    __syncthreads();

    // coalesced run copy-out
    int total = lbase[NBUCKET - 1] + lcnt[NBUCKET - 1];
    int cap = 8 * L;
    for (int i = tid; i < total; i += P1_THREADS) {
        int b = smap[i];
        int idx = gbase[b] + (i - lbase[b]);
        if (idx < cap)
            ell[(size_t)b * cap + idx] = stage[i];
    }
}

// ---------------- Phase 2: per-group, bin 8 buckets into 64 column lists, ----------------
// rewrite slab in place in the quad-interleaved ELL layout, zero-padded; write counts.
__global__ __launch_bounds__(P2_THREADS) void build_kernel(
        const int* __restrict__ bcnt, unsigned* __restrict__ ell,
        int* __restrict__ counts, int L) {
    __shared__ unsigned bins[64 * BIN_STRIDE];    // 41.2KB
    __shared__ int ccnt[64];
    __shared__ int qsh;
    int g = blockIdx.x;
    int tid = threadIdx.x;
    for (int i = tid; i < 64 * BIN_STRIDE; i += P2_THREADS) bins[i] = 0;
    if (tid < 64) ccnt[tid] = 0;
    __syncthreads();

    unsigned* slab = ell + (size_t)g * (64 * L);
    int cap = 8 * L;
#pragma unroll 1
    for (int q = 0; q < 8; ++q) {
        int cb = bcnt[g * 8 + q];
        if (cb > cap) cb = cap;
        const unsigned* bp = slab + q * cap;
        for (int i = tid; i < cb; i += P2_THREADS) {
            unsigned e = bp[i];
            int c64 = q * 8 + (int)(e & 7u);
            int rk = atomicAdd(&ccnt[c64], 1);
            if (rk < L) bins[c64 * BIN_STRIDE + rk] = e;
        }
    }
    __syncthreads();   // all bucket reads done -> safe to overwrite slab

    if (tid < 64) {
        int c = ccnt[tid];
        counts[g * 64 + tid] = c;
        int mc = min(c, L);
#pragma unroll
        for (int off = 32; off; off >>= 1) mc = max(mc, __shfl_xor(mc, off, 64));
        if (tid == 0) qsh = (mc + 3) >> 2;
    }
    __syncthreads();

    int D = qsh << 8;                              // quads * 256 dwords
    for (int d = tid; d < D; d += P2_THREADS) {
        int q = d >> 8, r = d & 255;
        slab[d] = bins[(r >> 2) * BIN_STRIDE + q * 4 + (r & 3)];
    }
}

#if USE_DOT2
// Process TWO ELL entries (same column, adjacent slots) against 8 staged batch rows.
__device__ __forceinline__ void process_pair8(unsigned pk0, unsigned pk1, const char* xbase,
        float& a0, float& a1, float& a2, float& a3,
        float& a4, float& a5, float& a6, float& a7) {
    unsigned off0 = pk0 & 0xFFF8u;               // row*8; LDS stride is 16 -> *2
    unsigned off1 = pk1 & 0xFFF8u;
    uint4 q0 = *(const uint4*)(xbase + off0 * 2);  // 8 f16: x[b0..b0+7][r0]
    uint4 q1 = *(const uint4*)(xbase + off1 * 2);  // 8 f16: x[b0..b0+7][r1]
    unsigned vv = __builtin_amdgcn_perm(pk1, pk0, 0x07060302u);
    half2v vh = __builtin_bit_cast(half2v, vv);
    unsigned e0 = __builtin_amdgcn_perm(q1.x, q0.x, 0x05040100u);
    unsigned o0 = __builtin_amdgcn_perm(q1.x, q0.x, 0x07060302u);
    unsigned e1 = __builtin_amdgcn_perm(q1.y, q0.y, 0x05040100u);
    unsigned o1 = __builtin_amdgcn_perm(q1.y, q0.y, 0x07060302u);
    unsigned e2 = __builtin_amdgcn_perm(q1.z, q0.z, 0x05040100u);
    unsigned o2 = __builtin_amdgcn_perm(q1.z, q0.z, 0x07060302u);
    unsigned e3 = __builtin_amdgcn_perm(q1.w, q0.w, 0x05040100u);
    unsigned o3 = __builtin_amdgcn_perm(q1.w, q0.w, 0x07060302u);
    a0 = __builtin_amdgcn_fdot2(__builtin_bit_cast(half2v, e0), vh, a0, false);
    a1 = __builtin_amdgcn_fdot2(__builtin_bit_cast(half2v, o0), vh, a1, false);
    a2 = __builtin_amdgcn_fdot2(__builtin_bit_cast(half2v, e1), vh, a2, false);
    a3 = __builtin_amdgcn_fdot2(__builtin_bit_cast(half2v, o1), vh, a3, false);
    a4 = __builtin_amdgcn_fdot2(__builtin_bit_cast(half2v, e2), vh, a4, false);
    a5 = __builtin_amdgcn_fdot2(__builtin_bit_cast(half2v, o2), vh, a5, false);
    a6 = __builtin_amdgcn_fdot2(__builtin_bit_cast(half2v, e3), vh, a6, false);
    a7 = __builtin_amdgcn_fdot2(__builtin_bit_cast(half2v, o3), vh, a7, false);
}
#else
__device__ __forceinline__ void process_entry8(unsigned pk, const char* xbase,
                                               f32x2& a01, f32x2& a23, f32x2& a45, f32x2& a67) {
    float val = bf16_hi_bits_to_f32(pk);
    f32x2 vv; vv.x = val; vv.y = val;
    unsigned off = pk & 0xFFF8u;
    uint4 d = *(const uint4*)(xbase + off * 2);
    a01 = __builtin_elementwise_fma(unpack_pair(d.x), vv, a01);
    a23 = __builtin_elementwise_fma(unpack_pair(d.y), vv, a23);
    a45 = __builtin_elementwise_fma(unpack_pair(d.z), vv, a45);
    a67 = __builtin_elementwise_fma(unpack_pair(d.w), vv, a67);
}
#endif

// Main SpMM: WG = (batch tile of 8) x (half the columns). 16 waves x 4 groups.
// 128KB dynamic LDS holds x[b0..b0+7, :] as uint4 (8 x 16-bit) per input row.
__global__ __launch_bounds__(MAIN_THREADS) void spmm_kernel(
        const float* __restrict__ x,
        const float* __restrict__ bias,
        const int* __restrict__ counts,
        const unsigned* __restrict__ ell,
        float* __restrict__ out, int L) {
    extern __shared__ uint4 xl[];               // IN_F entries = 128 KB
    int w = blockIdx.x;
    int bt = w >> 1;
    int half = w & 1;
    int t = threadIdx.x;
    int b0 = bt * BT;

    for (int r = t; r < IN_F; r += MAIN_THREADS) {
        unsigned u0 = x_bits(x[(b0 + 0) * IN_F + r]);
        unsigned u1 = x_bits(x[(b0 + 1) * IN_F + r]);
        unsigned u2 = x_bits(x[(b0 + 2) * IN_F + r]);
        unsigned u3 = x_bits(x[(b0 + 3) * IN_F + r]);
        unsigned u4 = x_bits(x[(b0 + 4) * IN_F + r]);
        unsigned u5 = x_bits(x[(b0 + 5) * IN_F + r]);
        unsigned u6 = x_bits(x[(b0 + 6) * IN_F + r]);
        unsigned u7 = x_bits(x[(b0 + 7) * IN_F + r]);
        uint4 d;
        d.x = (u1 << 16) | u0;
        d.y = (u3 << 16) | u2;
        d.z = (u5 << 16) | u4;
        d.w = (u7 << 16) | u6;
        xl[r] = d;
    }
    __syncthreads();

    const char* xbase = (const char*)xl;
    int wave = t >> 6;
    int lane = t & 63;
    int n4cap = L >> 2;

#pragma unroll 1
    for (int it = 0; it < GROUPS_PER_WAVE; ++it) {
        int g = half * 64 + wave * GROUPS_PER_WAVE + it;
        int col = (g << 6) + lane;
        int cnt = counts[col];
#pragma unroll
        for (int off = 32; off; off >>= 1) cnt = max(cnt, __shfl_xor(cnt, off, 64));
        int n4 = (cnt + 3) >> 2;
        n4 = min(n4, n4cap);
        const uint4* ep = (const uint4*)(ell + (size_t)g * (L * 64));
        float bv = bias[col];
#if USE_DOT2
        float a0 = 0.f, a1 = 0.f, a2 = 0.f, a3 = 0.f;
        float a4 = 0.f, a5 = 0.f, a6 = 0.f, a7 = 0.f;
        if (n4 > 0) {
            uint4 q = ep[lane];
#pragma unroll 1
            for (int s4 = 1; s4 < n4; ++s4) {
                uint4 qn = ep[s4 * 64 + lane];   // prefetch next (independent of q)
                process_pair8(q.x, q.y, xbase, a0, a1, a2, a3, a4, a5, a6, a7);
                process_pair8(q.z, q.w, xbase, a0, a1, a2, a3, a4, a5, a6, a7);
                q = qn;
            }
            process_pair8(q.x, q.y, xbase, a0, a1, a2, a3, a4, a5, a6, a7);
            process_pair8(q.z, q.w, xbase, a0, a1, a2, a3, a4, a5, a6, a7);
        }
        out[(size_t)(b0 + 0) * OUT_F + col] = a0 + bv;
        out[(size_t)(b0 + 1) * OUT_F + col] = a1 + bv;
        out[(size_t)(b0 + 2) * OUT_F + col] = a2 + bv;
        out[(size_t)(b0 + 3) * OUT_F + col] = a3 + bv;
        out[(size_t)(b0 + 4) * OUT_F + col] = a4 + bv;
        out[(size_t)(b0 + 5) * OUT_F + col] = a5 + bv;
        out[(size_t)(b0 + 6) * OUT_F + col] = a6 + bv;
        out[(size_t)(b0 + 7) * OUT_F + col] = a7 + bv;
#else
        f32x2 a01 = {0.f, 0.f}, a23 = {0.f, 0.f}, a45 = {0.f, 0.f}, a67 = {0.f, 0.f};
        if (n4 > 0) {
            uint4 q = ep[lane];
#pragma unroll 1
            for (int s4 = 1; s4 < n4; ++s4) {
                uint4 qn = ep[s4 * 64 + lane];
                process_entry8(q.x, xbase, a01, a23, a45, a67);
                process_entry8(q.y, xbase, a01, a23, a45, a67);
                process_entry8(q.z, xbase, a01, a23, a45, a67);
                process_entry8(q.w, xbase, a01, a23, a45, a67);
                q = qn;
            }
            process_entry8(q.x, xbase, a01, a23, a45, a67);
            process_entry8(q.y, xbase, a01, a23, a45, a67);
            process_entry8(q.z, xbase, a01, a23, a45, a67);
            process_entry8(q.w, xbase, a01, a23, a45, a67);
        }
        out[(size_t)(b0 + 0) * OUT_F + col] = a01.x + bv;
        out[(size_t)(b0 + 1) * OUT_F + col] = a01.y + bv;
        out[(size_t)(b0 + 2) * OUT_F + col] = a23.x + bv;
        out[(size_t)(b0 + 3) * OUT_F + col] = a23.y + bv;
        out[(size_t)(b0 + 4) * OUT_F + col] = a45.x + bv;
        out[(size_t)(b0 + 5) * OUT_F + col] = a45.y + bv;
        out[(size_t)(b0 + 6) * OUT_F + col] = a67.x + bv;
        out[(size_t)(b0 + 7) * OUT_F + col] = a67.y + bv;
#endif
    }
}

extern "C" void kernel_launch(void* const* d_in, const int* in_sizes, int n_in,
                              void* d_out, int out_size, void* d_ws, size_t ws_size,
                              hipStream_t stream) {
    const float* x      = (const float*)d_in[0];
    const float* values = (const float*)d_in[1];
    const float* bias   = (const float*)d_in[2];
    const int* rows = (const int*)d_in[3];
    const int* cols = (const int*)d_in[4];
    float* out = (float*)d_out;
    int nnz = in_sizes[1];

    int* bcnt   = (int*)d_ws;                    // 1024 dwords
    int* counts = bcnt + NBUCKET;                // 8192 dwords
    unsigned* ell = (unsigned*)(counts + 8192);  // 128 * 64 * L dwords

    // L = slots per column, multiple of 4, clamped to workspace capacity.
    long long cap_slots = ((long long)(ws_size / 4) - (NBUCKET + 8192)) / 8192;
    int L = (int)(cap_slots & ~3LL);
    if (L > L_PREF) L = L_PREF;
    if (L < 4) L = 4;

    static int attr_set = -1;                    // host-side only; no device effect
    if (attr_set < 0) {
        hipFuncSetAttribute((const void*)spmm_kernel,
                            hipFuncAttributeMaxDynamicSharedMemorySize, XTILE_BYTES);
        attr_set = 1;
    }

    hipMemsetAsync(bcnt, 0, NBUCKET * 4, stream);   // only bucket counters need zeroing
    int nb1 = (nnz + P1_CHUNK - 1) / P1_CHUNK;
    bin_kernel<<<nb1, P1_THREADS, 0, stream>>>(rows, cols, values, bcnt, ell, nnz, L);
    build_kernel<<<128, P2_THREADS, 0, stream>>>(bcnt, ell, counts, L);
    spmm_kernel<<<NBT * 2, MAIN_THREADS, XTILE_BYTES, stream>>>(x, bias, counts, ell, out, L);
}